// Round 6
// baseline (643.305 us; speedup 1.0000x reference)
//
#include <hip/hip_runtime.h>

namespace {
constexpr int kB = 8;
constexpr int kC = 64;
constexpr int kN = 100000;
constexpr int kR = 32;
constexpr int kR3 = kR * kR * kR;                     // 32768
constexpr size_t kGridElems = (size_t)kB * kC * kR3;  // 16,777,216
constexpr int kNV = kB * kR3;                         // 262144 voxel bins

// ws layout (bytes)
constexpr size_t kDsumOff = 0;                               // 192 B
constexpr size_t kMaxOff = 192;                              // 32 B
constexpr size_t kBsumOff = 1024;                            // 1 KB (256 uint)
constexpr size_t kCountsOff = 4096;                          // 1 MB
constexpr size_t kOffsetsOff = kCountsOff + (size_t)kNV * 4; // 1 MB
constexpr size_t kCursorOff = kOffsetsOff + (size_t)kNV * 4; // 1 MB
constexpr size_t kHashOff = kCursorOff + (size_t)kNV * 4;    // u16 x 800000
constexpr size_t kRankOff = kHashOff + (size_t)kB * kN * 2;  // u32 x 800000
constexpr size_t kFeatTOff = kRankOff + (size_t)kB * kN * 4;
inline size_t wsNeed(int chunkB) { return kFeatTOff + (size_t)chunkB * kN * kC * 4; }
}  // namespace

// ---------------- Kernel A: per-batch coordinate sums (double) ----------------
__global__ __launch_bounds__(256) void mean_kernel(const float* __restrict__ coords,
                                                   double* __restrict__ dsum) {
  const int b = blockIdx.y;
  const int tid = blockIdx.x * blockDim.x + threadIdx.x;
  const int stride = gridDim.x * blockDim.x;
  const float* cb = coords + (size_t)b * 3 * kN;
  double s0 = 0.0, s1 = 0.0, s2 = 0.0;
  for (int n = tid; n < kN; n += stride) {
    s0 += (double)cb[n];
    s1 += (double)cb[kN + n];
    s2 += (double)cb[2 * kN + n];
  }
  __shared__ double sh[3][256];
  sh[0][threadIdx.x] = s0;
  sh[1][threadIdx.x] = s1;
  sh[2][threadIdx.x] = s2;
  __syncthreads();
  for (int off = 128; off > 0; off >>= 1) {
    if (threadIdx.x < (unsigned)off) {
      sh[0][threadIdx.x] += sh[0][threadIdx.x + off];
      sh[1][threadIdx.x] += sh[1][threadIdx.x + off];
      sh[2][threadIdx.x] += sh[2][threadIdx.x + off];
    }
    __syncthreads();
  }
  if (threadIdx.x == 0) {
    atomicAdd(&dsum[b * 3 + 0], sh[0][0]);
    atomicAdd(&dsum[b * 3 + 1], sh[1][0]);
    atomicAdd(&dsum[b * 3 + 2], sh[2][0]);
  }
}

// ------------- Kernel B: per-batch max of squared norm (f32, no fma) ----------
__global__ __launch_bounds__(256) void maxnorm_kernel(const float* __restrict__ coords,
                                                      const double* __restrict__ dsum,
                                                      unsigned* __restrict__ maxbits) {
#pragma clang fp contract(off)
  const int b = blockIdx.y;
  const int tid = blockIdx.x * blockDim.x + threadIdx.x;
  const int stride = gridDim.x * blockDim.x;
  const float* cb = coords + (size_t)b * 3 * kN;
  const float m0 = (float)(dsum[b * 3 + 0] / (double)kN);
  const float m1 = (float)(dsum[b * 3 + 1] / (double)kN);
  const float m2 = (float)(dsum[b * 3 + 2] / (double)kN);
  float mx = 0.0f;
  for (int n = tid; n < kN; n += stride) {
    float x = cb[n] - m0;
    float y = cb[kN + n] - m1;
    float z = cb[2 * kN + n] - m2;
    float sx = x * x;
    float sy = y * y;
    float sz = z * z;
    float s = (sx + sy) + sz;  // match numpy's non-fused order
    mx = fmaxf(mx, s);
  }
  __shared__ float sh[256];
  sh[threadIdx.x] = mx;
  __syncthreads();
  for (int off = 128; off > 0; off >>= 1) {
    if (threadIdx.x < (unsigned)off)
      sh[threadIdx.x] = fmaxf(sh[threadIdx.x], sh[threadIdx.x + off]);
    __syncthreads();
  }
  if (threadIdx.x == 0) atomicMax(&maxbits[b], __float_as_uint(sh[0]));
}

// ---------- common per-point geometry: returns h[4], writes norm_coords ------
__device__ __forceinline__ void point_geom(const float* __restrict__ coords,
                                           const double* __restrict__ dsum,
                                           const unsigned* __restrict__ maxbits,
                                           float* __restrict__ out_nc, int b, int n0,
                                           int h[4]) {
#pragma clang fp contract(off)
  const float m0 = (float)(dsum[b * 3 + 0] / (double)kN);
  const float m1 = (float)(dsum[b * 3 + 1] / (double)kN);
  const float m2 = (float)(dsum[b * 3 + 2] / (double)kN);
  const float scale = 2.0f * sqrtf(__uint_as_float(maxbits[b]));

  const float* cb = coords + (size_t)b * 3 * kN;
  const float4 cx = *(const float4*)(cb + n0);
  const float4 cy = *(const float4*)(cb + kN + n0);
  const float4 cz = *(const float4*)(cb + 2 * kN + n0);

  float xa[4] = {cx.x, cx.y, cx.z, cx.w};
  float ya[4] = {cy.x, cy.y, cy.z, cy.w};
  float za[4] = {cz.x, cz.y, cz.z, cz.w};
  float vx[4], vy[4], vz[4];
#pragma unroll
  for (int k = 0; k < 4; ++k) {
    float tx = (xa[k] - m0) / scale + 0.5f;
    float ty = (ya[k] - m1) / scale + 0.5f;
    float tz = (za[k] - m2) / scale + 0.5f;
    vx[k] = fminf(fmaxf(tx * 32.0f, 0.0f), 31.0f);
    vy[k] = fminf(fmaxf(ty * 32.0f, 0.0f), 31.0f);
    vz[k] = fminf(fmaxf(tz * 32.0f, 0.0f), 31.0f);
    int ix = (int)rintf(vx[k]);
    int iy = (int)rintf(vy[k]);
    int iz = (int)rintf(vz[k]);
    h[k] = ix * (kR * kR) + iy * kR + iz;
  }
  float* nb = out_nc + (size_t)b * 3 * kN;
  *(float4*)(nb + n0) = make_float4(vx[0], vx[1], vx[2], vx[3]);
  *(float4*)(nb + kN + n0) = make_float4(vy[0], vy[1], vy[2], vy[3]);
  *(float4*)(nb + 2 * kN + n0) = make_float4(vz[0], vz[1], vz[2], vz[3]);
}

// ----- Kernel C: hash + norm_coords + count histogram (800k uint atomics) -----
__global__ __launch_bounds__(256) void hash_nc_kernel(
    const float* __restrict__ coords, const double* __restrict__ dsum,
    const unsigned* __restrict__ maxbits, float* __restrict__ out_nc,
    unsigned short* __restrict__ hashes, unsigned* __restrict__ counts) {
  const int b = blockIdx.y;
  const int n0 = (blockIdx.x * 256 + threadIdx.x) * 4;
  if (n0 >= kN) return;
  int h[4];
  point_geom(coords, dsum, maxbits, out_nc, b, n0, h);
  ushort4 h4;
  h4.x = (unsigned short)h[0];
  h4.y = (unsigned short)h[1];
  h4.z = (unsigned short)h[2];
  h4.w = (unsigned short)h[3];
  *(ushort4*)(hashes + (size_t)b * kN + n0) = h4;
  unsigned* cnt = counts + (size_t)b * kR3;
  atomicAdd(&cnt[h[0]], 1u);
  atomicAdd(&cnt[h[1]], 1u);
  atomicAdd(&cnt[h[2]], 1u);
  atomicAdd(&cnt[h[3]], 1u);
}

// --------------------------- scan (3 kernels) --------------------------------
__global__ __launch_bounds__(256) void scan_reduce(const unsigned* __restrict__ counts,
                                                   unsigned* __restrict__ bsum) {
  __shared__ unsigned sh[256];
  const int t = threadIdx.x;
  const uint4 c = ((const uint4*)counts)[blockIdx.x * 256 + t];
  sh[t] = c.x + c.y + c.z + c.w;
  __syncthreads();
  for (int off = 128; off > 0; off >>= 1) {
    if (t < off) sh[t] += sh[t + off];
    __syncthreads();
  }
  if (t == 0) bsum[blockIdx.x] = sh[0];
}

__global__ __launch_bounds__(256) void scan_bsum(unsigned* __restrict__ bsum) {
  __shared__ unsigned sh[256];
  const int t = threadIdx.x;
  const unsigned v = bsum[t];
  sh[t] = v;
  __syncthreads();
  for (int d = 1; d < 256; d <<= 1) {
    const unsigned x = (t >= d) ? sh[t - d] : 0u;
    __syncthreads();
    sh[t] += x;
    __syncthreads();
  }
  bsum[t] = sh[t] - v;  // exclusive
}

__global__ __launch_bounds__(256) void scan_write(const unsigned* __restrict__ counts,
                                                  const unsigned* __restrict__ bsum,
                                                  unsigned* __restrict__ offsets,
                                                  unsigned* __restrict__ cursor) {
  __shared__ unsigned sh[256];
  const int t = threadIdx.x;
  const int gi = blockIdx.x * 256 + t;
  const uint4 c = ((const uint4*)counts)[gi];
  const unsigned tot = c.x + c.y + c.z + c.w;
  sh[t] = tot;
  __syncthreads();
  for (int d = 1; d < 256; d <<= 1) {
    const unsigned x = (t >= d) ? sh[t - d] : 0u;
    __syncthreads();
    sh[t] += x;
    __syncthreads();
  }
  const unsigned base = bsum[blockIdx.x] + sh[t] - tot;
  uint4 o;
  o.x = base;
  o.y = o.x + c.x;
  o.z = o.y + c.y;
  o.w = o.z + c.z;
  ((uint4*)offsets)[gi] = o;
  ((uint4*)cursor)[gi] = o;
}

// --------- Kernel E: claim slots -> inverse permutation rank[n] --------------
__global__ __launch_bounds__(256) void rank_kernel(const unsigned short* __restrict__ hashes,
                                                   unsigned* __restrict__ cursor,
                                                   unsigned* __restrict__ rank) {
  const int b = blockIdx.y;
  const int n0 = (blockIdx.x * 256 + threadIdx.x) * 4;
  if (n0 >= kN) return;
  const ushort4 h4 = *(const ushort4*)(hashes + (size_t)b * kN + n0);
  unsigned* cur = cursor + (size_t)b * kR3;
  uint4 r;
  r.x = atomicAdd(&cur[h4.x], 1u);
  r.y = atomicAdd(&cur[h4.y], 1u);
  r.z = atomicAdd(&cur[h4.z], 1u);
  r.w = atomicAdd(&cur[h4.w], 1u);
  *(uint4*)(rank + (size_t)b * kN + n0) = r;
}

// --- Kernel F: transpose feat (B,C,N) -> SORTED rows feat_t[rank[n]][c] ------
__global__ __launch_bounds__(256) void tr_kernel(const float* __restrict__ feat,
                                                 const unsigned* __restrict__ rank,
                                                 float* __restrict__ feat_t, int b0) {
  const int b2 = blockIdx.y;
  const int b = b0 + b2;
  const int n0 = blockIdx.x * 32;
  __shared__ float tile[64][33];
  __shared__ unsigned shr[32];
  if (threadIdx.x < 32) shr[threadIdx.x] = rank[(size_t)b * kN + n0 + threadIdx.x];
  const float* fb = feat + (size_t)b * kC * kN;
#pragma unroll
  for (int j = 0; j < 2; ++j) {
    const int idx = j * 256 + threadIdx.x;  // 0..511
    const int c = idx >> 3;
    const int q = idx & 7;
    const float4 v = *(const float4*)(fb + (size_t)c * kN + n0 + q * 4);
    tile[c][q * 4 + 0] = v.x;
    tile[c][q * 4 + 1] = v.y;
    tile[c][q * 4 + 2] = v.z;
    tile[c][q * 4 + 3] = v.w;
  }
  __syncthreads();
  const size_t rowbase = (size_t)b0 * kN;
#pragma unroll
  for (int j = 0; j < 2; ++j) {
    const int idx = j * 256 + threadIdx.x;  // 0..511
    const int n = idx >> 4;
    const int cq = idx & 15;
    float4 w;
    w.x = tile[cq * 4 + 0][n];
    w.y = tile[cq * 4 + 1][n];
    w.z = tile[cq * 4 + 2][n];
    w.w = tile[cq * 4 + 3][n];
    const size_t row = (size_t)shr[n] - rowbase;
    *(float4*)(feat_t + row * kC + cq * 4) = w;
  }
}

// --- Kernel G: persistent waves, grid-stride over voxels; 16 rows in flight --
__global__ __launch_bounds__(256) void gather_kernel(const float* __restrict__ feat_t,
                                                     const unsigned* __restrict__ offsets,
                                                     const unsigned* __restrict__ cursor,
                                                     float* __restrict__ out, int b0,
                                                     int chunkB) {
  const int nWaves = gridDim.x * 4;  // 8192 persistent waves
  const int wid = blockIdx.x * 4 + (threadIdx.x >> 6);
  const int lane = threadIdx.x & 63;
  const int p = lane & 15;  // row slot 0..15
  const int g = lane >> 4;  // channel group: channels [g*16, g*16+16)
  const int totV = chunkB * kR3;
  const unsigned rb = (unsigned)b0 * (unsigned)kN;

  for (int wv = wid; wv < totV; wv += nWaves) {
    const int b2 = wv >> 15;
    const int h = wv & (kR3 - 1);
    const int vg = (b0 + b2) * kR3 + h;
    const unsigned s = offsets[vg];
    const unsigned e = cursor[vg];  // segment end after rank_kernel claims
    if (s == e) continue;

    float4 a0 = make_float4(0.f, 0.f, 0.f, 0.f);
    float4 a1 = make_float4(0.f, 0.f, 0.f, 0.f);
    float4 a2 = make_float4(0.f, 0.f, 0.f, 0.f);
    float4 a3 = make_float4(0.f, 0.f, 0.f, 0.f);
    for (unsigned i = s + (unsigned)p; i < e; i += 16) {
      const float* rp = feat_t + (size_t)(i - rb) * kC + g * 16;
      const float4 f0 = *(const float4*)(rp);
      const float4 f1 = *(const float4*)(rp + 4);
      const float4 f2 = *(const float4*)(rp + 8);
      const float4 f3 = *(const float4*)(rp + 12);
      a0.x += f0.x; a0.y += f0.y; a0.z += f0.z; a0.w += f0.w;
      a1.x += f1.x; a1.y += f1.y; a1.z += f1.z; a1.w += f1.w;
      a2.x += f2.x; a2.y += f2.y; a2.z += f2.z; a2.w += f2.w;
      a3.x += f3.x; a3.y += f3.y; a3.z += f3.z; a3.w += f3.w;
    }
    // reduce across the 16 row slots (lane bits 0..3)
#pragma unroll
    for (int m = 1; m <= 8; m <<= 1) {
      a0.x += __shfl_xor(a0.x, m); a0.y += __shfl_xor(a0.y, m);
      a0.z += __shfl_xor(a0.z, m); a0.w += __shfl_xor(a0.w, m);
      a1.x += __shfl_xor(a1.x, m); a1.y += __shfl_xor(a1.y, m);
      a1.z += __shfl_xor(a1.z, m); a1.w += __shfl_xor(a1.w, m);
      a2.x += __shfl_xor(a2.x, m); a2.y += __shfl_xor(a2.y, m);
      a2.z += __shfl_xor(a2.z, m); a2.w += __shfl_xor(a2.w, m);
      a3.x += __shfl_xor(a3.x, m); a3.y += __shfl_xor(a3.y, m);
      a3.z += __shfl_xor(a3.z, m); a3.w += __shfl_xor(a3.w, m);
    }
    // all 16 lanes of each g-group now hold the 16 channel sums; lane p picks
    // channel g*16+p and all 64 lanes store one value in a single instruction.
    const int q = p >> 2;
    const int j = p & 3;
    const float4 aq = (q == 0) ? a0 : (q == 1) ? a1 : (q == 2) ? a2 : a3;
    const float val = (j == 0) ? aq.x : (j == 1) ? aq.y : (j == 2) ? aq.z : aq.w;
    const float k = (float)(e - s);
    out[((size_t)(b0 + b2) * kC + (g * 16 + p)) * kR3 + h] = val / k;
  }
}

// --------------- Fallback: direct atomics into out (b,c,h) -------------------
__global__ __launch_bounds__(256) void scatter_direct(
    const float* __restrict__ feat, const float* __restrict__ coords,
    const double* __restrict__ dsum, const unsigned* __restrict__ maxbits,
    float* __restrict__ gridsum, float* __restrict__ out_nc,
    unsigned* __restrict__ counts) {
  const int b = blockIdx.y;
  const int n0 = (blockIdx.x * 256 + threadIdx.x) * 4;
  if (n0 >= kN) return;
  int h[4];
  point_geom(coords, dsum, maxbits, out_nc, b, n0, h);
  unsigned* cnt = counts + (size_t)b * kR3;
  atomicAdd(&cnt[h[0]], 1u);
  atomicAdd(&cnt[h[1]], 1u);
  atomicAdd(&cnt[h[2]], 1u);
  atomicAdd(&cnt[h[3]], 1u);
  const float* fb = feat + (size_t)b * kC * kN + n0;
  float* gb = gridsum + (size_t)b * kC * kR3;
#pragma unroll 8
  for (int c = 0; c < kC; ++c) {
    const float4 f = *(const float4*)(fb + (size_t)c * kN);
    float* g = gb + (size_t)c * kR3;
    unsafeAtomicAdd(g + h[0], f.x);
    unsafeAtomicAdd(g + h[1], f.y);
    unsafeAtomicAdd(g + h[2], f.z);
    unsafeAtomicAdd(g + h[3], f.w);
  }
}

__global__ __launch_bounds__(256) void divide_inplace(float* __restrict__ grid,
                                                      const unsigned* __restrict__ counts) {
  const size_t e = ((size_t)blockIdx.x * blockDim.x + threadIdx.x) * 4;
  if (e >= kGridElems) return;
  const int h = (int)(e & (size_t)(kR3 - 1));
  const int b = (int)(e >> 21);
  const uint4 cnt = *(const uint4*)(counts + (size_t)b * kR3 + h);
  float4 g = *(float4*)(grid + e);
  g.x = g.x / (float)(cnt.x > 1u ? cnt.x : 1u);
  g.y = g.y / (float)(cnt.y > 1u ? cnt.y : 1u);
  g.z = g.z / (float)(cnt.z > 1u ? cnt.z : 1u);
  g.w = g.w / (float)(cnt.w > 1u ? cnt.w : 1u);
  *(float4*)(grid + e) = g;
}

extern "C" void kernel_launch(void* const* d_in, const int* in_sizes, int n_in,
                              void* d_out, int out_size, void* d_ws, size_t ws_size,
                              hipStream_t stream) {
  const float* feat = (const float*)d_in[0];    // (8, 64, 100000)
  const float* coords = (const float*)d_in[1];  // (8, 3, 100000)
  float* out = (float*)d_out;
  float* out_nc = out + kGridElems;  // (8, 3, 100000)

  char* ws = (char*)d_ws;
  double* dsum = (double*)(ws + kDsumOff);
  unsigned* maxbits = (unsigned*)(ws + kMaxOff);
  unsigned* bsum = (unsigned*)(ws + kBsumOff);
  unsigned* counts = (unsigned*)(ws + kCountsOff);
  unsigned* offsets = (unsigned*)(ws + kOffsetsOff);
  unsigned* cursor = (unsigned*)(ws + kCursorOff);
  unsigned short* hashes = (unsigned short*)(ws + kHashOff);
  unsigned* rank = (unsigned*)(ws + kRankOff);
  float* feat_t = (float*)(ws + kFeatTOff);

  const dim3 blk(256);
  const int pblk = (kN / 4 + 255) / 256;  // 98 point-blocks per batch

  // zero header + counts (rest is fully rewritten each call)
  hipMemsetAsync(ws, 0, kCountsOff + (size_t)kNV * sizeof(unsigned), stream);

  mean_kernel<<<dim3(32, kB), blk, 0, stream>>>(coords, dsum);
  maxnorm_kernel<<<dim3(32, kB), blk, 0, stream>>>(coords, dsum, maxbits);

  int chunkB = 0;
  for (int c = kB; c >= 1; c >>= 1) {
    if (ws_size >= wsNeed(c)) { chunkB = c; break; }
  }

  if (chunkB) {
    hash_nc_kernel<<<dim3(pblk, kB), blk, 0, stream>>>(coords, dsum, maxbits, out_nc,
                                                       hashes, counts);
    scan_reduce<<<dim3(256), blk, 0, stream>>>(counts, bsum);
    scan_bsum<<<dim3(1), blk, 0, stream>>>(bsum);
    scan_write<<<dim3(256), blk, 0, stream>>>(counts, bsum, offsets, cursor);
    rank_kernel<<<dim3(pblk, kB), blk, 0, stream>>>(hashes, cursor, rank);

    // zero the grid region; gather writes only occupied voxels
    hipMemsetAsync(out, 0, kGridElems * sizeof(float), stream);

    for (int b0 = 0; b0 < kB; b0 += chunkB) {
      tr_kernel<<<dim3(kN / 32, chunkB), blk, 0, stream>>>(feat, rank, feat_t, b0);
      gather_kernel<<<dim3(2048), blk, 0, stream>>>(feat_t, offsets, cursor, out, b0,
                                                    chunkB);
    }
  } else {
    // fallback: direct atomics into final layout
    hipMemsetAsync(out, 0, kGridElems * sizeof(float), stream);
    scatter_direct<<<dim3(pblk, kB), blk, 0, stream>>>(feat, coords, dsum, maxbits, out,
                                                       out_nc, counts);
    const size_t vec4 = kGridElems / 4;
    divide_inplace<<<dim3((unsigned)((vec4 + 255) / 256)), blk, 0, stream>>>(out, counts);
  }
}

// Round 7
// 311.608 us; speedup vs baseline: 2.0645x; 2.0645x over previous
//
#include <hip/hip_runtime.h>

namespace {
constexpr int kB = 8;
constexpr int kC = 64;
constexpr int kN = 100000;
constexpr int kR = 32;
constexpr int kR3 = kR * kR * kR;                     // 32768
constexpr size_t kGridElems = (size_t)kB * kC * kR3;  // 16,777,216
constexpr int kNV = kB * kR3;                         // 262144 voxel bins

// ws layout (bytes)
constexpr size_t kDsumOff = 0;                                 // 192 B
constexpr size_t kMaxOff = 192;                                // 32 B
constexpr size_t kBsumOff = 1024;                              // 1 KB (256 uint)
constexpr size_t kCountsOff = 4096;                            // 1 MB
constexpr size_t kOffsetsOff = kCountsOff + (size_t)kNV * 4;   // (kNV+1) uints
constexpr size_t kHashOff = kOffsetsOff + (size_t)(kNV + 64) * 4;  // u16 x 800000
constexpr size_t kLrOff = kHashOff + (size_t)kB * kN * 2;      // u32 x 800000
constexpr size_t kFeatTOff = kLrOff + (size_t)kB * kN * 4;
inline size_t wsNeed(int chunkB) { return kFeatTOff + (size_t)chunkB * kN * kC * 4; }
}  // namespace

__device__ __forceinline__ void f4add(float4& a, const float4& f) {
  a.x += f.x; a.y += f.y; a.z += f.z; a.w += f.w;
}
__device__ __forceinline__ void f4red(float4& a) {
  a.x += __shfl_xor(a.x, 16); a.y += __shfl_xor(a.y, 16);
  a.z += __shfl_xor(a.z, 16); a.w += __shfl_xor(a.w, 16);
  a.x += __shfl_xor(a.x, 32); a.y += __shfl_xor(a.y, 32);
  a.z += __shfl_xor(a.z, 32); a.w += __shfl_xor(a.w, 32);
}

// ---------------- Kernel A: per-batch coordinate sums (double) ----------------
__global__ __launch_bounds__(256) void mean_kernel(const float* __restrict__ coords,
                                                   double* __restrict__ dsum) {
  const int b = blockIdx.y;
  const int tid = blockIdx.x * blockDim.x + threadIdx.x;
  const int stride = gridDim.x * blockDim.x;
  const float* cb = coords + (size_t)b * 3 * kN;
  double s0 = 0.0, s1 = 0.0, s2 = 0.0;
  for (int n = tid; n < kN; n += stride) {
    s0 += (double)cb[n];
    s1 += (double)cb[kN + n];
    s2 += (double)cb[2 * kN + n];
  }
  __shared__ double sh[3][256];
  sh[0][threadIdx.x] = s0;
  sh[1][threadIdx.x] = s1;
  sh[2][threadIdx.x] = s2;
  __syncthreads();
  for (int off = 128; off > 0; off >>= 1) {
    if (threadIdx.x < (unsigned)off) {
      sh[0][threadIdx.x] += sh[0][threadIdx.x + off];
      sh[1][threadIdx.x] += sh[1][threadIdx.x + off];
      sh[2][threadIdx.x] += sh[2][threadIdx.x + off];
    }
    __syncthreads();
  }
  if (threadIdx.x == 0) {
    atomicAdd(&dsum[b * 3 + 0], sh[0][0]);
    atomicAdd(&dsum[b * 3 + 1], sh[1][0]);
    atomicAdd(&dsum[b * 3 + 2], sh[2][0]);
  }
}

// ------------- Kernel B: per-batch max of squared norm (f32, no fma) ----------
__global__ __launch_bounds__(256) void maxnorm_kernel(const float* __restrict__ coords,
                                                      const double* __restrict__ dsum,
                                                      unsigned* __restrict__ maxbits) {
#pragma clang fp contract(off)
  const int b = blockIdx.y;
  const int tid = blockIdx.x * blockDim.x + threadIdx.x;
  const int stride = gridDim.x * blockDim.x;
  const float* cb = coords + (size_t)b * 3 * kN;
  const float m0 = (float)(dsum[b * 3 + 0] / (double)kN);
  const float m1 = (float)(dsum[b * 3 + 1] / (double)kN);
  const float m2 = (float)(dsum[b * 3 + 2] / (double)kN);
  float mx = 0.0f;
  for (int n = tid; n < kN; n += stride) {
    float x = cb[n] - m0;
    float y = cb[kN + n] - m1;
    float z = cb[2 * kN + n] - m2;
    float sx = x * x;
    float sy = y * y;
    float sz = z * z;
    float s = (sx + sy) + sz;  // match numpy's non-fused order
    mx = fmaxf(mx, s);
  }
  __shared__ float sh[256];
  sh[threadIdx.x] = mx;
  __syncthreads();
  for (int off = 128; off > 0; off >>= 1) {
    if (threadIdx.x < (unsigned)off)
      sh[threadIdx.x] = fmaxf(sh[threadIdx.x], sh[threadIdx.x + off]);
    __syncthreads();
  }
  if (threadIdx.x == 0) atomicMax(&maxbits[b], __float_as_uint(sh[0]));
}

// ---------- common per-point geometry: returns h[4], writes norm_coords ------
__device__ __forceinline__ void point_geom(const float* __restrict__ coords,
                                           const double* __restrict__ dsum,
                                           const unsigned* __restrict__ maxbits,
                                           float* __restrict__ out_nc, int b, int n0,
                                           int h[4]) {
#pragma clang fp contract(off)
  const float m0 = (float)(dsum[b * 3 + 0] / (double)kN);
  const float m1 = (float)(dsum[b * 3 + 1] / (double)kN);
  const float m2 = (float)(dsum[b * 3 + 2] / (double)kN);
  const float scale = 2.0f * sqrtf(__uint_as_float(maxbits[b]));

  const float* cb = coords + (size_t)b * 3 * kN;
  const float4 cx = *(const float4*)(cb + n0);
  const float4 cy = *(const float4*)(cb + kN + n0);
  const float4 cz = *(const float4*)(cb + 2 * kN + n0);

  float xa[4] = {cx.x, cx.y, cx.z, cx.w};
  float ya[4] = {cy.x, cy.y, cy.z, cy.w};
  float za[4] = {cz.x, cz.y, cz.z, cz.w};
  float vx[4], vy[4], vz[4];
#pragma unroll
  for (int k = 0; k < 4; ++k) {
    float tx = (xa[k] - m0) / scale + 0.5f;
    float ty = (ya[k] - m1) / scale + 0.5f;
    float tz = (za[k] - m2) / scale + 0.5f;
    vx[k] = fminf(fmaxf(tx * 32.0f, 0.0f), 31.0f);
    vy[k] = fminf(fmaxf(ty * 32.0f, 0.0f), 31.0f);
    vz[k] = fminf(fmaxf(tz * 32.0f, 0.0f), 31.0f);
    int ix = (int)rintf(vx[k]);
    int iy = (int)rintf(vy[k]);
    int iz = (int)rintf(vz[k]);
    h[k] = ix * (kR * kR) + iy * kR + iz;
  }
  float* nb = out_nc + (size_t)b * 3 * kN;
  *(float4*)(nb + n0) = make_float4(vx[0], vx[1], vx[2], vx[3]);
  *(float4*)(nb + kN + n0) = make_float4(vy[0], vy[1], vy[2], vy[3]);
  *(float4*)(nb + 2 * kN + n0) = make_float4(vz[0], vz[1], vz[2], vz[3]);
}

// - Kernel C: hash + nc + count histogram + local rank (800k uint atomics) ----
__global__ __launch_bounds__(256) void hash_nc_kernel(
    const float* __restrict__ coords, const double* __restrict__ dsum,
    const unsigned* __restrict__ maxbits, float* __restrict__ out_nc,
    unsigned short* __restrict__ hashes, unsigned* __restrict__ lr,
    unsigned* __restrict__ counts) {
  const int b = blockIdx.y;
  const int n0 = (blockIdx.x * 256 + threadIdx.x) * 4;
  if (n0 >= kN) return;
  int h[4];
  point_geom(coords, dsum, maxbits, out_nc, b, n0, h);
  ushort4 h4;
  h4.x = (unsigned short)h[0];
  h4.y = (unsigned short)h[1];
  h4.z = (unsigned short)h[2];
  h4.w = (unsigned short)h[3];
  *(ushort4*)(hashes + (size_t)b * kN + n0) = h4;
  unsigned* cnt = counts + (size_t)b * kR3;
  uint4 l;
  l.x = atomicAdd(&cnt[h[0]], 1u);
  l.y = atomicAdd(&cnt[h[1]], 1u);
  l.z = atomicAdd(&cnt[h[2]], 1u);
  l.w = atomicAdd(&cnt[h[3]], 1u);
  *(uint4*)(lr + (size_t)b * kN + n0) = l;
}

// --------------------------- scan (3 kernels) --------------------------------
__global__ __launch_bounds__(256) void scan_reduce(const unsigned* __restrict__ counts,
                                                   unsigned* __restrict__ bsum) {
  __shared__ unsigned sh[256];
  const int t = threadIdx.x;
  const uint4 c = ((const uint4*)counts)[blockIdx.x * 256 + t];
  sh[t] = c.x + c.y + c.z + c.w;
  __syncthreads();
  for (int off = 128; off > 0; off >>= 1) {
    if (t < off) sh[t] += sh[t + off];
    __syncthreads();
  }
  if (t == 0) bsum[blockIdx.x] = sh[0];
}

__global__ __launch_bounds__(256) void scan_bsum(unsigned* __restrict__ bsum) {
  __shared__ unsigned sh[256];
  const int t = threadIdx.x;
  const unsigned v = bsum[t];
  sh[t] = v;
  __syncthreads();
  for (int d = 1; d < 256; d <<= 1) {
    const unsigned x = (t >= d) ? sh[t - d] : 0u;
    __syncthreads();
    sh[t] += x;
    __syncthreads();
  }
  bsum[t] = sh[t] - v;  // exclusive
}

__global__ __launch_bounds__(256) void scan_write(const unsigned* __restrict__ counts,
                                                  const unsigned* __restrict__ bsum,
                                                  unsigned* __restrict__ offsets) {
  __shared__ unsigned sh[256];
  const int t = threadIdx.x;
  const int gi = blockIdx.x * 256 + t;
  const uint4 c = ((const uint4*)counts)[gi];
  const unsigned tot = c.x + c.y + c.z + c.w;
  sh[t] = tot;
  __syncthreads();
  for (int d = 1; d < 256; d <<= 1) {
    const unsigned x = (t >= d) ? sh[t - d] : 0u;
    __syncthreads();
    sh[t] += x;
    __syncthreads();
  }
  const unsigned base = bsum[blockIdx.x] + sh[t] - tot;
  uint4 o;
  o.x = base;
  o.y = o.x + c.x;
  o.z = o.y + c.y;
  o.w = o.z + c.z;
  ((uint4*)offsets)[gi] = o;
  if (gi == kNV / 4 - 1) offsets[kNV] = o.w + c.w;  // total = B*N
}

// --- Kernel F: transpose feat (B,C,N) -> SORTED rows feat_t[off[h]+lr][c] ----
__global__ __launch_bounds__(256) void tr_kernel(const float* __restrict__ feat,
                                                 const unsigned short* __restrict__ hashes,
                                                 const unsigned* __restrict__ lr,
                                                 const unsigned* __restrict__ offsets,
                                                 float* __restrict__ feat_t, int b0) {
  const int b2 = blockIdx.y;
  const int b = b0 + b2;
  const int n0 = blockIdx.x * 32;
  __shared__ float tile[64][33];
  __shared__ unsigned shr[32];
  if (threadIdx.x < 32) {
    const int n = n0 + threadIdx.x;
    const unsigned hh = hashes[(size_t)b * kN + n];
    const unsigned l = lr[(size_t)b * kN + n];
    shr[threadIdx.x] = offsets[(size_t)b * kR3 + hh] + l - (unsigned)b0 * (unsigned)kN;
  }
  const float* fb = feat + (size_t)b * kC * kN;
#pragma unroll
  for (int j = 0; j < 2; ++j) {
    const int idx = j * 256 + threadIdx.x;  // 0..511
    const int c = idx >> 3;
    const int q = idx & 7;
    const float4 v = *(const float4*)(fb + (size_t)c * kN + n0 + q * 4);
    tile[c][q * 4 + 0] = v.x;
    tile[c][q * 4 + 1] = v.y;
    tile[c][q * 4 + 2] = v.z;
    tile[c][q * 4 + 3] = v.w;
  }
  __syncthreads();
#pragma unroll
  for (int j = 0; j < 2; ++j) {
    const int idx = j * 256 + threadIdx.x;  // 0..511
    const int n = idx >> 4;
    const int cq = idx & 15;
    float4 w;
    w.x = tile[cq * 4 + 0][n];
    w.y = tile[cq * 4 + 1][n];
    w.z = tile[cq * 4 + 2][n];
    w.w = tile[cq * 4 + 3][n];
    const size_t row = (size_t)shr[n];
    *(float4*)(feat_t + row * kC + cq * 4) = w;
  }
}

// --- Kernel G: one-shot wave per 4 consecutive voxels; streaming union range --
__global__ __launch_bounds__(256) void gather_kernel(const float* __restrict__ feat_t,
                                                     const unsigned* __restrict__ offsets,
                                                     float* __restrict__ out, int b0) {
  const int wid = blockIdx.x * 4 + (threadIdx.x >> 6);
  const int lane = threadIdx.x & 63;
  const int p = lane >> 4;   // row slot / component select, 0..3
  const int cq = lane & 15;  // channel quad 0..15
  const int v0 = wid * 4;    // first of 4 consecutive voxels (within chunk)
  const int b2 = v0 >> 15;
  const int h0 = v0 & (kR3 - 1);
  const int vgl = b0 * kR3 + v0;  // global voxel index (4-aligned)

  const uint4 o4 = *(const uint4*)(offsets + vgl);
  const unsigned e3 = offsets[vgl + 4];
  const unsigned s0 = o4.x, e0 = o4.y, e1 = o4.z, e2 = o4.w;
  const unsigned rb = (unsigned)b0 * (unsigned)kN;

  float4 a0 = make_float4(0.f, 0.f, 0.f, 0.f);
  float4 a1 = make_float4(0.f, 0.f, 0.f, 0.f);
  float4 a2 = make_float4(0.f, 0.f, 0.f, 0.f);
  float4 a3 = make_float4(0.f, 0.f, 0.f, 0.f);

  for (unsigned r = s0 + (unsigned)p; r < e3; r += 4) {
    const float4 f = *(const float4*)(feat_t + (size_t)(r - rb) * kC + cq * 4);
    if (r < e0)      f4add(a0, f);
    else if (r < e1) f4add(a1, f);
    else if (r < e2) f4add(a2, f);
    else             f4add(a3, f);
  }
  if (e3 != s0) {  // skip cross-lane work for fully-empty quads
    f4red(a0);
    f4red(a1);
    f4red(a2);
    f4red(a3);
  }
  const float k0 = (e0 > s0) ? (float)(e0 - s0) : 1.0f;
  const float k1 = (e1 > e0) ? (float)(e1 - e0) : 1.0f;
  const float k2 = (e2 > e1) ? (float)(e2 - e1) : 1.0f;
  const float k3 = (e3 > e2) ? (float)(e3 - e2) : 1.0f;
  const float w0 = (p == 0) ? a0.x : (p == 1) ? a0.y : (p == 2) ? a0.z : a0.w;
  const float w1 = (p == 0) ? a1.x : (p == 1) ? a1.y : (p == 2) ? a1.z : a1.w;
  const float w2 = (p == 0) ? a2.x : (p == 1) ? a2.y : (p == 2) ? a2.z : a2.w;
  const float w3 = (p == 0) ? a3.x : (p == 1) ? a3.y : (p == 2) ? a3.z : a3.w;
  float* ob = out + ((size_t)(b0 + b2) * kC + (cq * 4 + p)) * kR3 + h0;
  ob[0] = w0 / k0;
  ob[1] = w1 / k1;
  ob[2] = w2 / k2;
  ob[3] = w3 / k3;
}

// --------------- Fallback: direct atomics into out (b,c,h) -------------------
__global__ __launch_bounds__(256) void scatter_direct(
    const float* __restrict__ feat, const float* __restrict__ coords,
    const double* __restrict__ dsum, const unsigned* __restrict__ maxbits,
    float* __restrict__ gridsum, float* __restrict__ out_nc,
    unsigned* __restrict__ counts) {
  const int b = blockIdx.y;
  const int n0 = (blockIdx.x * 256 + threadIdx.x) * 4;
  if (n0 >= kN) return;
  int h[4];
  point_geom(coords, dsum, maxbits, out_nc, b, n0, h);
  unsigned* cnt = counts + (size_t)b * kR3;
  atomicAdd(&cnt[h[0]], 1u);
  atomicAdd(&cnt[h[1]], 1u);
  atomicAdd(&cnt[h[2]], 1u);
  atomicAdd(&cnt[h[3]], 1u);
  const float* fb = feat + (size_t)b * kC * kN + n0;
  float* gb = gridsum + (size_t)b * kC * kR3;
#pragma unroll 8
  for (int c = 0; c < kC; ++c) {
    const float4 f = *(const float4*)(fb + (size_t)c * kN);
    float* g = gb + (size_t)c * kR3;
    unsafeAtomicAdd(g + h[0], f.x);
    unsafeAtomicAdd(g + h[1], f.y);
    unsafeAtomicAdd(g + h[2], f.z);
    unsafeAtomicAdd(g + h[3], f.w);
  }
}

__global__ __launch_bounds__(256) void divide_inplace(float* __restrict__ grid,
                                                      const unsigned* __restrict__ counts) {
  const size_t e = ((size_t)blockIdx.x * blockDim.x + threadIdx.x) * 4;
  if (e >= kGridElems) return;
  const int h = (int)(e & (size_t)(kR3 - 1));
  const int b = (int)(e >> 21);
  const uint4 cnt = *(const uint4*)(counts + (size_t)b * kR3 + h);
  float4 g = *(float4*)(grid + e);
  g.x = g.x / (float)(cnt.x > 1u ? cnt.x : 1u);
  g.y = g.y / (float)(cnt.y > 1u ? cnt.y : 1u);
  g.z = g.z / (float)(cnt.z > 1u ? cnt.z : 1u);
  g.w = g.w / (float)(cnt.w > 1u ? cnt.w : 1u);
  *(float4*)(grid + e) = g;
}

extern "C" void kernel_launch(void* const* d_in, const int* in_sizes, int n_in,
                              void* d_out, int out_size, void* d_ws, size_t ws_size,
                              hipStream_t stream) {
  const float* feat = (const float*)d_in[0];    // (8, 64, 100000)
  const float* coords = (const float*)d_in[1];  // (8, 3, 100000)
  float* out = (float*)d_out;
  float* out_nc = out + kGridElems;  // (8, 3, 100000)

  char* ws = (char*)d_ws;
  double* dsum = (double*)(ws + kDsumOff);
  unsigned* maxbits = (unsigned*)(ws + kMaxOff);
  unsigned* bsum = (unsigned*)(ws + kBsumOff);
  unsigned* counts = (unsigned*)(ws + kCountsOff);
  unsigned* offsets = (unsigned*)(ws + kOffsetsOff);
  unsigned short* hashes = (unsigned short*)(ws + kHashOff);
  unsigned* lr = (unsigned*)(ws + kLrOff);
  float* feat_t = (float*)(ws + kFeatTOff);

  const dim3 blk(256);
  const int pblk = (kN / 4 + 255) / 256;  // 98 point-blocks per batch

  // zero header + counts (rest is fully rewritten each call)
  hipMemsetAsync(ws, 0, kCountsOff + (size_t)kNV * sizeof(unsigned), stream);

  mean_kernel<<<dim3(32, kB), blk, 0, stream>>>(coords, dsum);
  maxnorm_kernel<<<dim3(32, kB), blk, 0, stream>>>(coords, dsum, maxbits);

  int chunkB = 0;
  for (int c = kB; c >= 1; c >>= 1) {
    if (ws_size >= wsNeed(c)) { chunkB = c; break; }
  }

  if (chunkB) {
    hash_nc_kernel<<<dim3(pblk, kB), blk, 0, stream>>>(coords, dsum, maxbits, out_nc,
                                                       hashes, lr, counts);
    scan_reduce<<<dim3(256), blk, 0, stream>>>(counts, bsum);
    scan_bsum<<<dim3(1), blk, 0, stream>>>(bsum);
    scan_write<<<dim3(256), blk, 0, stream>>>(counts, bsum, offsets);

    for (int b0 = 0; b0 < kB; b0 += chunkB) {
      tr_kernel<<<dim3(kN / 32, chunkB), blk, 0, stream>>>(feat, hashes, lr, offsets,
                                                           feat_t, b0);
      gather_kernel<<<dim3(chunkB * (kR3 / 16)), blk, 0, stream>>>(feat_t, offsets, out,
                                                                   b0);
    }
  } else {
    // fallback: direct atomics into final layout
    hipMemsetAsync(out, 0, kGridElems * sizeof(float), stream);
    scatter_direct<<<dim3(pblk, kB), blk, 0, stream>>>(feat, coords, dsum, maxbits, out,
                                                       out_nc, counts);
    const size_t vec4 = kGridElems / 4;
    divide_inplace<<<dim3((unsigned)((vec4 + 255) / 256)), blk, 0, stream>>>(out, counts);
  }
}